// Round 9
// baseline (88.650 us; speedup 1.0000x reference)
//
#include <hip/hip_runtime.h>
#include <hip/hip_bf16.h>

typedef __bf16 bf16x8 __attribute__((ext_vector_type(8)));
typedef float  f32x4  __attribute__((ext_vector_type(4)));

static constexpr int E    = 1965;   // J*D + J*3
static constexpr int KF   = 1920;   // J*D
static constexpr int NJ   = 15;
static constexpr int NCLS = 68;
static constexpr int NPAD = 80;     // 5 tiles of 16
static constexpr int NT   = 5;
static constexpr int NS   = 60;     // k-steps of 32
static constexpr int CH   = 12;     // K-chunks of 5 k-steps (160 fp32 cols)

// ws layout:
//   pnf: [NT][NS][64][8] __bf16  = 307200 B
//   pa : [NPAD][45] float        = 14400 B
static constexpr size_t PNF_BYTES = (size_t)NT * NS * 64 * 8 * 2;

// ---------------- kernel 1: normalize W -> bf16 fragments + angle extract ----
__global__ __launch_bounds__(256) void prep_kernel(const float* __restrict__ W,
                                                   __bf16* __restrict__ pnf,
                                                   float* __restrict__ pa) {
    const int n = blockIdx.x;      // 0..79
    const int t = threadIdx.x;     // 0..255
    float v[8];
    float ss = 0.f;
    if (n < NCLS && t < 240) {
        const float* src = W + (size_t)n * E + 8 * t;
        #pragma unroll
        for (int i = 0; i < 8; ++i) { v[i] = src[i]; ss += v[i] * v[i]; }
    } else {
        #pragma unroll
        for (int i = 0; i < 8; ++i) v[i] = 0.f;
    }
    #pragma unroll
    for (int off = 32; off >= 1; off >>= 1) ss += __shfl_xor(ss, off);
    __shared__ float rbuf[4];
    if ((t & 63) == 0) rbuf[t >> 6] = ss;
    __syncthreads();
    const float total = rbuf[0] + rbuf[1] + rbuf[2] + rbuf[3];
    const float rnorm = 1.f / fmaxf(sqrtf(total), 1e-12f);

    if (t < 240) {
        bf16x8 o;
        #pragma unroll
        for (int i = 0; i < 8; ++i) o[i] = (__bf16)(v[i] * rnorm);
        const int s = t >> 2, g = t & 3;
        const int lane = (n & 15) + 16 * g;
        const size_t off = (((size_t)(n >> 4) * NS + s) * 64 + lane) * 8;
        *(bf16x8*)(pnf + off) = o;
    }
    if (t < 45) {
        pa[n * 45 + t] = (n < NCLS) ? W[(size_t)n * E + KF + t] : 0.f;
    }
}

// ---------------- kernel 2: all-DMA double-buffered GEMM + fused epilogue ----
// Per chunk (160 fp32 k-cols): each of 5 waves issues exactly 7 global_load_lds
// (2 for A-fp32, 5 for its B-tile). __syncthreads() == vmcnt(0)+barrier is the
// chunk wait; chunk c+1's flight hides under compute(c). No MFMA operand ever
// passes through a staging VGPR.
// A swizzle: physical unit p holds logical unit g with p = g ^ ((g>>3)&7)
// (involution; mask from bits 3-5, which the XOR leaves unchanged). Read side
// must fetch logical g0+1 at p0^1 (NOT p0+1: mask bit0 may make p0 odd).
__global__ __launch_bounds__(320) void cos_kernel(const float* __restrict__ emb,
                                                  const __bf16* __restrict__ pnf,
                                                  const float* __restrict__ pa,
                                                  float* __restrict__ out) {
    __shared__ float  Abuf[2][2560];     // [buf][(2*step+rg)*256 + unit*4], 20,480 B
    __shared__ __bf16 Bbuf[2][25][512];  // [buf][w*5+s][lane*8],            51,200 B
    __shared__ float  xa[16][48];        //                                   3,072 B

    const int tid = threadIdx.x;
    const int m0  = blockIdx.x * 16;
    const int w   = tid >> 6;    // wave = N-tile 0..4 (wave-uniform)
    const int l   = tid & 63;
    const int lr  = l & 15;      // A row / B col within tile
    const int lg  = l >> 4;      // k-group

    // ---- xa staging (ordered by first __syncthreads) ----
    for (int idx = tid; idx < 16 * 45; idx += 320) {
        const int r = idx / 45, c = idx - r * 45;
        xa[r][c] = emb[(size_t)(m0 + r) * E + KF + c];
    }

    // ---- A-DMA source decode: physical unit l sources logical gA ----
    const int gA   = l ^ ((l >> 3) & 7);
    const int arow = (gA >> 1) & 15;
    const float* srcA = emb + (size_t)(m0 + arow) * E + 8 * (gA >> 5) + 4 * (gA & 1)
                        + 32 * w;                   // + 160*c + 16*b at issue
    // B-DMA source: lane-linear fragment stream of this wave's tile
    const __bf16* srcB = pnf + ((size_t)w * NS * 64 + l) * 8;   // + (5c+s)*512

    #define ISSUE(c, buf)                                                               \
        {                                                                               \
            _Pragma("unroll")                                                           \
            for (int b_ = 0; b_ < 2; ++b_)                                              \
                __builtin_amdgcn_global_load_lds(                                       \
                    (const __attribute__((address_space(1))) void*)(srcA + 160 * (c) + 16 * b_), \
                    (__attribute__((address_space(3))) void*)&Abuf[buf][(2 * w + b_) * 256],     \
                    16, 0, 0);                                                          \
            _Pragma("unroll")                                                           \
            for (int s_ = 0; s_ < 5; ++s_)                                              \
                __builtin_amdgcn_global_load_lds(                                       \
                    (const __attribute__((address_space(1))) void*)(srcB + (5 * (c) + s_) * 512),\
                    (__attribute__((address_space(3))) void*)&Bbuf[buf][w * 5 + s_][0],          \
                    16, 0, 0);                                                          \
        }

    // read-side A address: lane wants logical units g0 (alo) and g0+1 (ahi)
    const int g0    = 32 * (lg & 1) + 2 * lr;
    const int p_lo  = g0 ^ ((g0 >> 3) & 7);
    const int p_hi  = p_lo ^ 1;                     // logical g0+1 placement
    const int aoff_lo = (lg >> 1) * 256 + 4 * p_lo; // + s*512 per step
    const int aoff_hi = (lg >> 1) * 256 + 4 * p_hi;

    f32x4 acc[NJ];
    #pragma unroll
    for (int j = 0; j < NJ; ++j) acc[j] = f32x4{0.f, 0.f, 0.f, 0.f};
    float ssq = 0.f;

    ISSUE(0, 0);

    #pragma unroll
    for (int c = 0; c < CH; ++c) {
        __syncthreads();                 // vmcnt(0): chunk c landed; prev readers done
        if (c + 1 < CH) ISSUE(c + 1, (c + 1) & 1);

        #pragma unroll
        for (int s = 0; s < 5; ++s) {
            const f32x4 alo = *(const f32x4*)&Abuf[c & 1][s * 512 + aoff_lo];
            const f32x4 ahi = *(const f32x4*)&Abuf[c & 1][s * 512 + aoff_hi];
            const bf16x8 b  = *(const bf16x8*)&Bbuf[c & 1][w * 5 + s][l * 8];
            bf16x8 af;
            #pragma unroll
            for (int q = 0; q < 4; ++q) {
                ssq += alo[q] * alo[q] + ahi[q] * ahi[q];
                af[q]     = (__bf16)alo[q];
                af[4 + q] = (__bf16)ahi[q];
            }
            const int gk = 5 * c + s;
            acc[gk >> 2] = __builtin_amdgcn_mfma_f32_16x16x32_bf16(af, b, acc[gk >> 2], 0, 0, 0);
        }
    }
    #undef ISSUE

    // ---- row norms: lanes {lr, lr+16, lr+32, lr+48} hold row-lr partials ----
    ssq += __shfl_xor(ssq, 16);
    ssq += __shfl_xor(ssq, 32);

    const int r0  = lg * 4;      // C/D: row = (lane>>4)*4 + reg, col = lane&15
    const int col = w * 16 + lr;

    float rn[4];
    #pragma unroll
    for (int r = 0; r < 4; ++r)
        rn[r] = 240.f / fmaxf(sqrtf(__shfl(ssq, r0 + r)), 1e-12f);   // 16*15/norm

    // ---- angle softmax epilogue (pa is 14.4 KB, L2-hot) ----
    const float* pav = pa + col * 45;
    float num[4] = {0.f, 0.f, 0.f, 0.f};
    float den[4] = {0.f, 0.f, 0.f, 0.f};
    #pragma unroll
    for (int j = 0; j < NJ; ++j) {
        const float p0a = pav[3 * j + 0];
        const float p1a = pav[3 * j + 1];
        const float p2a = pav[3 * j + 2];
        #pragma unroll
        for (int r = 0; r < 4; ++r) {
            const float d0 = xa[r0 + r][3 * j + 0] - p0a;
            const float d1 = xa[r0 + r][3 * j + 1] - p1a;
            const float d2 = xa[r0 + r][3 * j + 2] - p2a;
            const float dist = sqrtf(d0 * d0 + d1 * d1 + d2 * d2);
            const float e = __expf(dist * 0.005f);   // exponents in [0, ~0.05]
            den[r] += e;
            num[r] += e * acc[j][r];
        }
    }

    if (col < NCLS) {
        #pragma unroll
        for (int r = 0; r < 4; ++r)
            out[(size_t)(m0 + r0 + r) * NCLS + col] = rn[r] * num[r] / den[r];
    }
}

extern "C" void kernel_launch(void* const* d_in, const int* in_sizes, int n_in,
                              void* d_out, int out_size, void* d_ws, size_t ws_size,
                              hipStream_t stream) {
    const float* emb = (const float*)d_in[0];
    const float* W   = (const float*)d_in[1];
    float* out = (float*)d_out;
    __bf16* pnf = (__bf16*)d_ws;
    float*  pa  = (float*)((char*)d_ws + PNF_BYTES);
    const int B = in_sizes[0] / E;           // 16384

    prep_kernel<<<NPAD, 256, 0, stream>>>(W, pnf, pa);
    cos_kernel<<<B / 16, 320, 0, stream>>>(emb, pnf, pa, out);
}